// Round 1
// baseline (765.296 us; speedup 1.0000x reference)
//
#include <hip/hip_runtime.h>
#include <stdint.h>

typedef float v4f __attribute__((ext_vector_type(4)));
typedef short v8s __attribute__((ext_vector_type(8)));

constexpr int Bq = 4, Tq = 8192, Dq = 1024, Fq = 4096;
constexpr int CAP = Tq / 2;     // 4096 tokens selected per batch row
constexpr int Mq  = Bq * CAP;   // 16384 routed tokens total

// ---------- helpers ----------
__device__ __forceinline__ unsigned short f2bf(float f) {
  unsigned int u = __float_as_uint(f);
  u += 0x7FFFu + ((u >> 16) & 1u);   // RNE
  return (unsigned short)(u >> 16);
}

__device__ __forceinline__ void async_cp16(const void* g, void* l) {
  // 16B/lane global->LDS DMA; LDS dest is wave-uniform base + lane*16
  __builtin_amdgcn_global_load_lds(
      (__attribute__((address_space(1))) void*)g,
      (__attribute__((address_space(3))) void*)l, 16, 0, 0);
}

// ---------- scores: s[b,t] = dot(x[b,t,:], w_router), fp64 accumulate ----------
__global__ void scores_kernel(const float* __restrict__ x,
                              const float* __restrict__ wr_g,
                              double* __restrict__ scores) {
  __shared__ __align__(16) float wr[Dq];
  for (int i = threadIdx.x; i < Dq; i += 256) wr[i] = wr_g[i];
  __syncthreads();
  int wid = threadIdx.x >> 6, lane = threadIdx.x & 63;
  int gw = blockIdx.x * 4 + wid;
  const float4* wp = (const float4*)wr;
  for (int rr = 0; rr < 4; ++rr) {
    int row = gw * 4 + rr;   // [0, B*T)
    const float4* xp = (const float4*)(x + (size_t)row * Dq);
    double s = 0.0;
#pragma unroll
    for (int q = 0; q < 4; ++q) {
      float4 v = xp[lane + q * 64];
      float4 w = wp[lane + q * 64];
      s += (double)v.x * w.x + (double)v.y * w.y + (double)v.z * w.z + (double)v.w * w.w;
    }
#pragma unroll
    for (int off = 32; off; off >>= 1) s += __shfl_down(s, off);
    if (lane == 0) scores[row] = s;
  }
}

// ---------- top-k select (exact, per batch row) ----------
__device__ __forceinline__ int block_reduce_i(int v, int* red, int tid) {
#pragma unroll
  for (int off = 32; off; off >>= 1) v += __shfl_down(v, off);
  __syncthreads();                       // protect red[] from previous call
  if ((tid & 63) == 0) red[tid >> 6] = v;
  __syncthreads();
  int s = 0;
#pragma unroll
  for (int k = 0; k < 16; ++k) s += red[k];
  return s;                              // same value in all threads
}

__global__ __launch_bounds__(1024) void select_topk(const double* __restrict__ scores,
                                                    int* __restrict__ selIdx,
                                                    unsigned char* __restrict__ selFlag) {
  int b = blockIdx.x, tid = threadIdx.x;
  const double* s = scores + (size_t)b * Tq;
  __shared__ int red[16];
  __shared__ int counter;
  unsigned long long key[8];
#pragma unroll
  for (int i = 0; i < 8; ++i) {
    unsigned long long u = (unsigned long long)__double_as_longlong(s[tid + i * 1024]);
    key[i] = (u >> 63) ? ~u : (u | 0x8000000000000000ULL);  // order-preserving map
  }
  // cutoff = max X with count(key >= X) >= CAP  (== CAP-th largest key)
  unsigned long long cutoff = 0ULL;
  for (int bit = 63; bit >= 0; --bit) {
    unsigned long long cand = cutoff | (1ULL << bit);
    int c = 0;
#pragma unroll
    for (int i = 0; i < 8; ++i) c += (key[i] >= cand) ? 1 : 0;
    int tot = block_reduce_i(c, red, tid);
    if (tot >= CAP) cutoff = cand;
  }
  int cGt = 0, cEq = 0;
#pragma unroll
  for (int i = 0; i < 8; ++i) { cGt += (key[i] > cutoff); cEq += (key[i] == cutoff); }
  int gtTot = block_reduce_i(cGt, red, tid);
  int eqTot = block_reduce_i(cEq, red, tid);
  int need = CAP - gtTot;                // ties to take (>=1)
  if (tid == 0) counter = 0;
  __syncthreads();
  bool takeAllEq = (eqTot == need);      // common case: no straddling duplicates
#pragma unroll
  for (int i = 0; i < 8; ++i) {
    int t = tid + i * 1024;
    bool sel = takeAllEq ? (key[i] >= cutoff) : (key[i] > cutoff);
    if (sel) { int pos = atomicAdd(&counter, 1); selIdx[b * CAP + pos] = t; }
    selFlag[(size_t)b * Tq + t] = sel ? (unsigned char)1 : (unsigned char)0;
  }
  if (!takeAllEq) {                      // rare: exact ties at cutoff, lowest index first
    __syncthreads();
    if (tid == 0) {
      int taken = 0;
      for (int t = 0; t < Tq && taken < need; ++t) {
        unsigned long long u = (unsigned long long)__double_as_longlong(s[t]);
        unsigned long long k = (u >> 63) ? ~u : (u | 0x8000000000000000ULL);
        if (k == cutoff) {
          selIdx[b * CAP + gtTot + taken] = t;
          selFlag[(size_t)b * Tq + t] = 1;
          ++taken;
        }
      }
    }
  }
}

// ---------- gather selected rows -> bf16 Xs [Mq, Dq] ----------
__global__ void gather_kernel(const float* __restrict__ x,
                              const int* __restrict__ selIdx,
                              unsigned short* __restrict__ Xs) {
  int wid = threadIdx.x >> 6, lane = threadIdx.x & 63;
  int m = blockIdx.x * 4 + wid;          // [0, Mq)
  int b = m >> 12;                       // CAP == 4096
  int tok = selIdx[m];
  const float4* src = (const float4*)(x + ((size_t)b * Tq + tok) * Dq);
  ushort4* dst = (ushort4*)(Xs + (size_t)m * Dq);
#pragma unroll
  for (int q = 0; q < 4; ++q) {
    float4 v = src[lane + q * 64];
    ushort4 o; o.x = f2bf(v.x); o.y = f2bf(v.y); o.z = f2bf(v.z); o.w = f2bf(v.w);
    dst[lane + q * 64] = o;
  }
}

// ---------- pass-through copy of unselected rows ----------
__global__ void copy_pass(const float* __restrict__ x,
                          const unsigned char* __restrict__ selFlag,
                          float* __restrict__ out) {
  int wid = threadIdx.x >> 6, lane = threadIdx.x & 63;
  int row = blockIdx.x * 4 + wid;        // [0, B*T)
  if (selFlag[row]) return;              // wave-uniform branch
  const float4* src = (const float4*)(x + (size_t)row * Dq);
  float4* dst = (float4*)(out + (size_t)row * Dq);
#pragma unroll
  for (int q = 0; q < 4; ++q) dst[lane + q * 64] = src[lane + q * 64];
}

// ---------- fp32 [R,C] -> bf16 transposed [C,R] ----------
__global__ void transpose_f32_to_bf16(const float* __restrict__ in,
                                      unsigned short* __restrict__ out,
                                      int R, int C) {
  __shared__ float tile[32][33];
  int tx = threadIdx.x, ty = threadIdx.y;          // (32, 8)
  int c0 = blockIdx.x * 32, r0 = blockIdx.y * 32;
#pragma unroll
  for (int k = 0; k < 4; ++k)
    tile[ty + k * 8][tx] = in[(size_t)(r0 + ty + k * 8) * C + c0 + tx];
  __syncthreads();
#pragma unroll
  for (int k = 0; k < 4; ++k)
    out[(size_t)(c0 + ty + k * 8) * R + r0 + tx] = f2bf(tile[tx][ty + k * 8]);
}

// ---------- GEMM1: H = gelu(Xs @ W1 + b1), bf16 out. A[rows,1024], Bt[4096,1024] ----------
__global__ __launch_bounds__(256) void gemm1_gelu(const unsigned short* __restrict__ A,
                                                  const unsigned short* __restrict__ Bt,
                                                  const float* __restrict__ bias,
                                                  unsigned short* __restrict__ H) {
  constexpr int K = Dq, N = Fq;
  __shared__ __align__(16) unsigned short As[128 * 32];
  __shared__ __align__(16) unsigned short Bs[128 * 32];
  const int tid = threadIdx.x;
  const int wid = tid >> 6, lane = tid & 63;
  const int wm = wid >> 1, wn = wid & 1;
  const int quad = lane >> 4, l16 = lane & 15;
  const int m0 = blockIdx.y * 128, n0 = blockIdx.x * 128;

  const int sRow = tid >> 2, sCol = (tid & 3) << 3;
  const unsigned short* aG0 = A + (size_t)(m0 + sRow) * K + sCol;
  const unsigned short* aG1 = aG0 + (size_t)64 * K;
  const unsigned short* bG0 = Bt + (size_t)(n0 + sRow) * K + sCol;
  const unsigned short* bG1 = bG0 + (size_t)64 * K;
  unsigned short* aL0 = As + wid * 512;
  unsigned short* aL1 = As + 2048 + wid * 512;
  unsigned short* bL0 = Bs + wid * 512;
  unsigned short* bL1 = Bs + 2048 + wid * 512;

  int aOff[4], bOff[4];
#pragma unroll
  for (int i = 0; i < 4; ++i) aOff[i] = (wm * 64 + i * 16 + l16) * 32 + quad * 8;
#pragma unroll
  for (int j = 0; j < 4; ++j) bOff[j] = (wn * 64 + j * 16 + l16) * 32 + quad * 8;

  v4f acc[4][4] = {};

  for (int k0 = 0; k0 < K; k0 += 32) {
    async_cp16(aG0 + k0, aL0);
    async_cp16(aG1 + k0, aL1);
    async_cp16(bG0 + k0, bL0);
    async_cp16(bG1 + k0, bL1);
    __syncthreads();                     // drains vmcnt before barrier
    v8s af[4], bfr[4];
#pragma unroll
    for (int i = 0; i < 4; ++i) af[i] = *(const v8s*)(As + aOff[i]);
#pragma unroll
    for (int j = 0; j < 4; ++j) bfr[j] = *(const v8s*)(Bs + bOff[j]);
#pragma unroll
    for (int i = 0; i < 4; ++i)
#pragma unroll
      for (int j = 0; j < 4; ++j)
        acc[i][j] = __builtin_amdgcn_mfma_f32_16x16x32_bf16(af[i], bfr[j], acc[i][j], 0, 0, 0);
    __syncthreads();                     // protect LDS before next stage
  }

  const int mBase = m0 + wm * 64, nBase = n0 + wn * 64;
#pragma unroll
  for (int i = 0; i < 4; ++i)
#pragma unroll
    for (int r = 0; r < 4; ++r) {
      const int row = mBase + i * 16 + quad * 4 + r;
      unsigned short* hp = H + (size_t)row * N;
#pragma unroll
      for (int j = 0; j < 4; ++j) {
        const int col = nBase + j * 16 + l16;
        float c = acc[i][j][r] + bias[col];
        // jax.nn.gelu approximate=True (tanh form), overflow-safe tanh
        float z = 0.7978845608028654f * (c + 0.044715f * c * c * c);
        float a = __expf(-2.0f * fabsf(z));
        float th = copysignf((1.0f - a) / (1.0f + a), z);
        hp[col] = f2bf(0.5f * c * (1.0f + th));
      }
    }
}

// ---------- GEMM2: out[sel rows] = H @ W2 + b2 (scatter). A[rows,4096], Bt[1024,4096] ----------
__global__ __launch_bounds__(256) void gemm2_scatter(const unsigned short* __restrict__ A,
                                                     const unsigned short* __restrict__ Bt,
                                                     const float* __restrict__ bias,
                                                     const int* __restrict__ selIdx,
                                                     float* __restrict__ out,
                                                     int chunkStart) {
  constexpr int K = Fq, N = Dq;
  __shared__ __align__(16) unsigned short As[128 * 32];
  __shared__ __align__(16) unsigned short Bs[128 * 32];
  const int tid = threadIdx.x;
  const int wid = tid >> 6, lane = tid & 63;
  const int wm = wid >> 1, wn = wid & 1;
  const int quad = lane >> 4, l16 = lane & 15;
  const int m0 = blockIdx.y * 128, n0 = blockIdx.x * 128;

  const int sRow = tid >> 2, sCol = (tid & 3) << 3;
  const unsigned short* aG0 = A + (size_t)(m0 + sRow) * K + sCol;
  const unsigned short* aG1 = aG0 + (size_t)64 * K;
  const unsigned short* bG0 = Bt + (size_t)(n0 + sRow) * K + sCol;
  const unsigned short* bG1 = bG0 + (size_t)64 * K;
  unsigned short* aL0 = As + wid * 512;
  unsigned short* aL1 = As + 2048 + wid * 512;
  unsigned short* bL0 = Bs + wid * 512;
  unsigned short* bL1 = Bs + 2048 + wid * 512;

  int aOff[4], bOff[4];
#pragma unroll
  for (int i = 0; i < 4; ++i) aOff[i] = (wm * 64 + i * 16 + l16) * 32 + quad * 8;
#pragma unroll
  for (int j = 0; j < 4; ++j) bOff[j] = (wn * 64 + j * 16 + l16) * 32 + quad * 8;

  v4f acc[4][4] = {};

  for (int k0 = 0; k0 < K; k0 += 32) {
    async_cp16(aG0 + k0, aL0);
    async_cp16(aG1 + k0, aL1);
    async_cp16(bG0 + k0, bL0);
    async_cp16(bG1 + k0, bL1);
    __syncthreads();
    v8s af[4], bfr[4];
#pragma unroll
    for (int i = 0; i < 4; ++i) af[i] = *(const v8s*)(As + aOff[i]);
#pragma unroll
    for (int j = 0; j < 4; ++j) bfr[j] = *(const v8s*)(Bs + bOff[j]);
#pragma unroll
    for (int i = 0; i < 4; ++i)
#pragma unroll
      for (int j = 0; j < 4; ++j)
        acc[i][j] = __builtin_amdgcn_mfma_f32_16x16x32_bf16(af[i], bfr[j], acc[i][j], 0, 0, 0);
    __syncthreads();
  }

  const int mBase = m0 + wm * 64, nBase = n0 + wn * 64;
#pragma unroll
  for (int i = 0; i < 4; ++i)
#pragma unroll
    for (int r = 0; r < 4; ++r) {
      const int lrow = mBase + i * 16 + quad * 4 + r;
      const int m = chunkStart + lrow;
      const int b = m >> 12;             // CAP == 4096
      const int tok = selIdx[m];
      float* op = out + ((size_t)b * Tq + tok) * Dq;
#pragma unroll
      for (int j = 0; j < 4; ++j) {
        const int col = nBase + j * 16 + l16;
        op[col] = acc[i][j][r] + bias[col];
      }
    }
}

// ---------- host ----------
extern "C" void kernel_launch(void* const* d_in, const int* in_sizes, int n_in,
                              void* d_out, int out_size, void* d_ws, size_t ws_size,
                              hipStream_t stream) {
  const float* x        = (const float*)d_in[0];
  const float* w_router = (const float*)d_in[1];
  const float* w1       = (const float*)d_in[2];
  const float* b1       = (const float*)d_in[3];
  const float* w2       = (const float*)d_in[4];
  const float* b2       = (const float*)d_in[5];
  float* out = (float*)d_out;

  char* p = (char*)d_ws;
  auto alloc = [&](size_t bytes) {
    char* r = p;
    p += (bytes + 255) & ~(size_t)255;
    return r;
  };
  double* scores          = (double*)alloc((size_t)Bq * Tq * 8);
  int* selIdx             = (int*)alloc((size_t)Mq * 4);
  unsigned char* selFlag  = (unsigned char*)alloc((size_t)Bq * Tq);
  unsigned short* W1t     = (unsigned short*)alloc((size_t)Dq * Fq * 2);  // [F, D]
  unsigned short* W2t     = (unsigned short*)alloc((size_t)Dq * Fq * 2);  // [D, F]
  unsigned short* Xs      = (unsigned short*)alloc((size_t)Mq * Dq * 2);  // [M, D]
  size_t used = (size_t)(p - (char*)d_ws);
  size_t rem = ws_size > used ? ws_size - used : 0;
  int chunkRows = (int)(rem / ((size_t)Fq * 2));
  chunkRows = (chunkRows / 128) * 128;
  if (chunkRows > Mq) chunkRows = Mq;
  if (chunkRows < 128) chunkRows = 128;   // requires ws_size >= ~49.4 MB
  unsigned short* H = (unsigned short*)p;  // [chunkRows, F] bf16

  transpose_f32_to_bf16<<<dim3(Fq / 32, Dq / 32), dim3(32, 8), 0, stream>>>(w1, W1t, Dq, Fq);
  transpose_f32_to_bf16<<<dim3(Dq / 32, Fq / 32), dim3(32, 8), 0, stream>>>(w2, W2t, Fq, Dq);
  scores_kernel<<<2048, 256, 0, stream>>>(x, w_router, scores);
  select_topk<<<Bq, 1024, 0, stream>>>(scores, selIdx, selFlag);
  gather_kernel<<<Mq / 4, 256, 0, stream>>>(x, selIdx, Xs);
  copy_pass<<<(Bq * Tq) / 4, 256, 0, stream>>>(x, selFlag, out);

  for (int r0 = 0; r0 < Mq; r0 += chunkRows) {
    int rows = (Mq - r0 < chunkRows) ? (Mq - r0) : chunkRows;
    gemm1_gelu<<<dim3(Fq / 128, rows / 128), 256, 0, stream>>>(
        Xs + (size_t)r0 * Dq, W1t, b1, H);
    gemm2_scatter<<<dim3(Dq / 128, rows / 128), 256, 0, stream>>>(
        H, W2t, b2, selIdx, out, r0);
  }
}

// Round 3
// 698.866 us; speedup vs baseline: 1.0951x; 1.0951x over previous
//
#include <hip/hip_runtime.h>
#include <stdint.h>

typedef float v4f __attribute__((ext_vector_type(4)));
typedef short v8s __attribute__((ext_vector_type(8)));

constexpr int Bq = 4, Tq = 8192, Dq = 1024, Fq = 4096;
constexpr int CAP = Tq / 2;     // 4096 tokens selected per batch row
constexpr int Mq  = Bq * CAP;   // 16384 routed tokens total

// ---------- helpers ----------
__device__ __forceinline__ unsigned short f2bf(float f) {
  unsigned int u = __float_as_uint(f);
  u += 0x7FFFu + ((u >> 16) & 1u);   // RNE
  return (unsigned short)(u >> 16);
}

__device__ __forceinline__ void async_cp16(const void* g, void* l) {
  // 16B/lane global->LDS DMA; LDS dest is wave-uniform base + lane*16
  __builtin_amdgcn_global_load_lds(
      (__attribute__((address_space(1))) void*)g,
      (__attribute__((address_space(3))) void*)l, 16, 0, 0);
}

// ---------- scores: s[b,t] = dot(x[b,t,:], w_router), fp64 accumulate ----------
__global__ void scores_kernel(const float* __restrict__ x,
                              const float* __restrict__ wr_g,
                              double* __restrict__ scores) {
  __shared__ __align__(16) float wr[Dq];
  for (int i = threadIdx.x; i < Dq; i += 256) wr[i] = wr_g[i];
  __syncthreads();
  int wid = threadIdx.x >> 6, lane = threadIdx.x & 63;
  int gw = blockIdx.x * 4 + wid;
  const float4* wp = (const float4*)wr;
  for (int rr = 0; rr < 4; ++rr) {
    int row = gw * 4 + rr;   // [0, B*T)
    const float4* xp = (const float4*)(x + (size_t)row * Dq);
    double s = 0.0;
#pragma unroll
    for (int q = 0; q < 4; ++q) {
      float4 v = xp[lane + q * 64];
      float4 w = wp[lane + q * 64];
      s += (double)v.x * w.x + (double)v.y * w.y + (double)v.z * w.z + (double)v.w * w.w;
    }
#pragma unroll
    for (int off = 32; off; off >>= 1) s += __shfl_down(s, off);
    if (lane == 0) scores[row] = s;
  }
}

// ---------- top-k select (exact, per batch row) ----------
__device__ __forceinline__ int block_reduce_i(int v, int* red, int tid) {
#pragma unroll
  for (int off = 32; off; off >>= 1) v += __shfl_down(v, off);
  __syncthreads();                       // protect red[] from previous call
  if ((tid & 63) == 0) red[tid >> 6] = v;
  __syncthreads();
  int s = 0;
#pragma unroll
  for (int k = 0; k < 16; ++k) s += red[k];
  return s;                              // same value in all threads
}

__global__ __launch_bounds__(1024) void select_topk(const double* __restrict__ scores,
                                                    int* __restrict__ selIdx,
                                                    unsigned char* __restrict__ selFlag) {
  int b = blockIdx.x, tid = threadIdx.x;
  const double* s = scores + (size_t)b * Tq;
  __shared__ int red[16];
  __shared__ int counter;
  unsigned long long key[8];
#pragma unroll
  for (int i = 0; i < 8; ++i) {
    unsigned long long u = (unsigned long long)__double_as_longlong(s[tid + i * 1024]);
    key[i] = (u >> 63) ? ~u : (u | 0x8000000000000000ULL);  // order-preserving map
  }
  // cutoff = max X with count(key >= X) >= CAP  (== CAP-th largest key)
  unsigned long long cutoff = 0ULL;
  for (int bit = 63; bit >= 0; --bit) {
    unsigned long long cand = cutoff | (1ULL << bit);
    int c = 0;
#pragma unroll
    for (int i = 0; i < 8; ++i) c += (key[i] >= cand) ? 1 : 0;
    int tot = block_reduce_i(c, red, tid);
    if (tot >= CAP) cutoff = cand;
  }
  int cGt = 0, cEq = 0;
#pragma unroll
  for (int i = 0; i < 8; ++i) { cGt += (key[i] > cutoff); cEq += (key[i] == cutoff); }
  int gtTot = block_reduce_i(cGt, red, tid);
  int eqTot = block_reduce_i(cEq, red, tid);
  int need = CAP - gtTot;                // ties to take (>=1)
  if (tid == 0) counter = 0;
  __syncthreads();
  bool takeAllEq = (eqTot == need);      // common case: no straddling duplicates
#pragma unroll
  for (int i = 0; i < 8; ++i) {
    int t = tid + i * 1024;
    bool sel = takeAllEq ? (key[i] >= cutoff) : (key[i] > cutoff);
    if (sel) { int pos = atomicAdd(&counter, 1); selIdx[b * CAP + pos] = t; }
    selFlag[(size_t)b * Tq + t] = sel ? (unsigned char)1 : (unsigned char)0;
  }
  if (!takeAllEq) {                      // rare: exact ties at cutoff, lowest index first
    __syncthreads();
    if (tid == 0) {
      int taken = 0;
      for (int t = 0; t < Tq && taken < need; ++t) {
        unsigned long long u = (unsigned long long)__double_as_longlong(s[t]);
        unsigned long long k = (u >> 63) ? ~u : (u | 0x8000000000000000ULL);
        if (k == cutoff) {
          selIdx[b * CAP + gtTot + taken] = t;
          selFlag[(size_t)b * Tq + t] = 1;
          ++taken;
        }
      }
    }
  }
}

// ---------- gather selected rows -> bf16 Xs [Mq, Dq] ----------
__global__ void gather_kernel(const float* __restrict__ x,
                              const int* __restrict__ selIdx,
                              unsigned short* __restrict__ Xs) {
  int wid = threadIdx.x >> 6, lane = threadIdx.x & 63;
  int m = blockIdx.x * 4 + wid;          // [0, Mq)
  int b = m >> 12;                       // CAP == 4096
  int tok = selIdx[m];
  const float4* src = (const float4*)(x + ((size_t)b * Tq + tok) * Dq);
  ushort4* dst = (ushort4*)(Xs + (size_t)m * Dq);
#pragma unroll
  for (int q = 0; q < 4; ++q) {
    float4 v = src[lane + q * 64];
    ushort4 o; o.x = f2bf(v.x); o.y = f2bf(v.y); o.z = f2bf(v.z); o.w = f2bf(v.w);
    dst[lane + q * 64] = o;
  }
}

// ---------- pass-through copy of unselected rows ----------
__global__ void copy_pass(const float* __restrict__ x,
                          const unsigned char* __restrict__ selFlag,
                          float* __restrict__ out) {
  int wid = threadIdx.x >> 6, lane = threadIdx.x & 63;
  int row = blockIdx.x * 4 + wid;        // [0, B*T)
  if (selFlag[row]) return;              // wave-uniform branch
  const float4* src = (const float4*)(x + (size_t)row * Dq);
  float4* dst = (float4*)(out + (size_t)row * Dq);
#pragma unroll
  for (int q = 0; q < 4; ++q) dst[lane + q * 64] = src[lane + q * 64];
}

// ---------- fp32 [R,C] -> bf16 transposed [C,R] ----------
__global__ void transpose_f32_to_bf16(const float* __restrict__ in,
                                      unsigned short* __restrict__ out,
                                      int R, int C) {
  __shared__ float tile[32][33];
  int tx = threadIdx.x, ty = threadIdx.y;          // (32, 8)
  int c0 = blockIdx.x * 32, r0 = blockIdx.y * 32;
#pragma unroll
  for (int k = 0; k < 4; ++k)
    tile[ty + k * 8][tx] = in[(size_t)(r0 + ty + k * 8) * C + c0 + tx];
  __syncthreads();
#pragma unroll
  for (int k = 0; k < 4; ++k)
    out[(size_t)(c0 + ty + k * 8) * R + r0 + tx] = f2bf(tile[tx][ty + k * 8]);
}

// LDS chunk swizzle: row's 16B chunk q stored at slot (q ^ ((row>>1)&3)).
// Staging stays lane-linear in LDS (global_load_lds constraint); only the
// per-lane GLOBAL source chunk changes (permutes within a 64B segment, so
// coalescing is unaffected). Believed conflict-NEUTRAL (collision multiset
// unchanged: rows alias pairwise at 64B stride) — kept as a free experiment;
// the SQ_LDS_BANK_CONFLICT counter adjudicates.

// ---------- GEMM1: H = gelu(Xs @ W1 + b1), bf16 out. A[rows,1024], Bt[4096,1024] ----------
__global__ __launch_bounds__(256) void gemm1_gelu(const unsigned short* __restrict__ A,
                                                  const unsigned short* __restrict__ Bt,
                                                  const float* __restrict__ bias,
                                                  unsigned short* __restrict__ H,
                                                  int nPanels) {
  constexpr int K = Dq, N = Fq;
  __shared__ __align__(16) unsigned short As[128 * 32];
  __shared__ __align__(16) unsigned short Bs[128 * 32];
  const int tid = threadIdx.x;
  const int wid = tid >> 6, lane = tid & 63;
  const int wm = wid >> 1, wn = wid & 1;
  const int quad = lane >> 4, l16 = lane & 15;

  // XCD panel-grouping: 32 n-tiles of one m-panel share blockIdx%8 (same XCD L2)
  int l = blockIdx.x;
  int pIdx, nIdx;
  if ((nPanels & 7) == 0) {
    nIdx = (l >> 3) & 31;
    pIdx = (l & 7) | ((l >> 8) << 3);
  } else {
    nIdx = l & 31;
    pIdx = l >> 5;
  }
  const int m0 = pIdx * 128, n0 = nIdx * 128;

  const int sRow = tid >> 2;
  const int sCol = (((tid & 3) ^ ((sRow >> 1) & 3)) << 3);   // swizzled source chunk
  const unsigned short* aG0 = A + (size_t)(m0 + sRow) * K + sCol;
  const unsigned short* aG1 = aG0 + (size_t)64 * K;
  const unsigned short* bG0 = Bt + (size_t)(n0 + sRow) * K + sCol;
  const unsigned short* bG1 = bG0 + (size_t)64 * K;
  unsigned short* aL0 = As + wid * 512;
  unsigned short* aL1 = As + 2048 + wid * 512;
  unsigned short* bL0 = Bs + wid * 512;
  unsigned short* bL1 = Bs + 2048 + wid * 512;

  const int swz = ((quad ^ ((l16 >> 1) & 3)) << 3);           // swizzled read slot
  int aOff[4], bOff[4];
#pragma unroll
  for (int i = 0; i < 4; ++i) aOff[i] = (wm * 64 + i * 16 + l16) * 32 + swz;
#pragma unroll
  for (int j = 0; j < 4; ++j) bOff[j] = (wn * 64 + j * 16 + l16) * 32 + swz;

  v4f acc[4][4] = {};

  for (int k0 = 0; k0 < K; k0 += 32) {
    async_cp16(aG0 + k0, aL0);
    async_cp16(aG1 + k0, aL1);
    async_cp16(bG0 + k0, bL0);
    async_cp16(bG1 + k0, bL1);
    __syncthreads();                     // drains vmcnt before barrier
    v8s af[4], bfr[4];
#pragma unroll
    for (int i = 0; i < 4; ++i) af[i] = *(const v8s*)(As + aOff[i]);
#pragma unroll
    for (int j = 0; j < 4; ++j) bfr[j] = *(const v8s*)(Bs + bOff[j]);
#pragma unroll
    for (int i = 0; i < 4; ++i)
#pragma unroll
      for (int j = 0; j < 4; ++j)
        acc[i][j] = __builtin_amdgcn_mfma_f32_16x16x32_bf16(af[i], bfr[j], acc[i][j], 0, 0, 0);
    __syncthreads();                     // protect LDS before next stage
  }

  const int mBase = m0 + wm * 64, nBase = n0 + wn * 64;
  float bv[4];
#pragma unroll
  for (int j = 0; j < 4; ++j) bv[j] = bias[nBase + j * 16 + l16];
  const float kA = 0.7978845608028654f, kB = 0.044715f * 0.7978845608028654f;
  const float kE = -2.0f * 1.4426950408889634f;   // exp(-2z) = exp2(kE*z)
#pragma unroll
  for (int i = 0; i < 4; ++i)
#pragma unroll
    for (int r = 0; r < 4; ++r) {
      const int row = mBase + i * 16 + quad * 4 + r;
      unsigned short* hp = H + (size_t)row * N;
#pragma unroll
      for (int j = 0; j < 4; ++j) {
        const int col = nBase + j * 16 + l16;
        float c = acc[i][j][r] + bv[j];
        float z = c * __builtin_fmaf(kB, c * c, kA);
        float a = exp2f(kE * fabsf(z));
        float th = copysignf((1.0f - a) * __builtin_amdgcn_rcpf(1.0f + a), z);
        hp[col] = f2bf(0.5f * c * (1.0f + th));
      }
    }
}

// ---------- GEMM2: out[sel rows] = H @ W2 + b2 (scatter). A[rows,4096], Bt[1024,4096] ----------
__global__ __launch_bounds__(256) void gemm2_scatter(const unsigned short* __restrict__ A,
                                                     const unsigned short* __restrict__ Bt,
                                                     const float* __restrict__ bias,
                                                     const int* __restrict__ selIdx,
                                                     float* __restrict__ out,
                                                     int chunkStart, int nPanels) {
  constexpr int K = Fq, N = Dq;
  __shared__ __align__(16) unsigned short As[128 * 32];
  __shared__ __align__(16) unsigned short Bs[128 * 32];
  const int tid = threadIdx.x;
  const int wid = tid >> 6, lane = tid & 63;
  const int wm = wid >> 1, wn = wid & 1;
  const int quad = lane >> 4, l16 = lane & 15;

  // XCD panel-grouping: 8 n-tiles of one m-panel share blockIdx%8 (same XCD L2)
  int l = blockIdx.x;
  int pIdx, nIdx;
  if ((nPanels & 7) == 0) {
    nIdx = (l >> 3) & 7;
    pIdx = (l & 7) | ((l >> 6) << 3);
  } else {
    nIdx = l & 7;
    pIdx = l >> 3;
  }
  const int m0 = pIdx * 128, n0 = nIdx * 128;

  const int sRow = tid >> 2;
  const int sCol = (((tid & 3) ^ ((sRow >> 1) & 3)) << 3);
  const unsigned short* aG0 = A + (size_t)(m0 + sRow) * K + sCol;
  const unsigned short* aG1 = aG0 + (size_t)64 * K;
  const unsigned short* bG0 = Bt + (size_t)(n0 + sRow) * K + sCol;
  const unsigned short* bG1 = bG0 + (size_t)64 * K;
  unsigned short* aL0 = As + wid * 512;
  unsigned short* aL1 = As + 2048 + wid * 512;
  unsigned short* bL0 = Bs + wid * 512;
  unsigned short* bL1 = Bs + 2048 + wid * 512;

  const int swz = ((quad ^ ((l16 >> 1) & 3)) << 3);
  int aOff[4], bOff[4];
#pragma unroll
  for (int i = 0; i < 4; ++i) aOff[i] = (wm * 64 + i * 16 + l16) * 32 + swz;
#pragma unroll
  for (int j = 0; j < 4; ++j) bOff[j] = (wn * 64 + j * 16 + l16) * 32 + swz;

  v4f acc[4][4] = {};

  for (int k0 = 0; k0 < K; k0 += 32) {
    async_cp16(aG0 + k0, aL0);
    async_cp16(aG1 + k0, aL1);
    async_cp16(bG0 + k0, bL0);
    async_cp16(bG1 + k0, bL1);
    __syncthreads();
    v8s af[4], bfr[4];
#pragma unroll
    for (int i = 0; i < 4; ++i) af[i] = *(const v8s*)(As + aOff[i]);
#pragma unroll
    for (int j = 0; j < 4; ++j) bfr[j] = *(const v8s*)(Bs + bOff[j]);
#pragma unroll
    for (int i = 0; i < 4; ++i)
#pragma unroll
      for (int j = 0; j < 4; ++j)
        acc[i][j] = __builtin_amdgcn_mfma_f32_16x16x32_bf16(af[i], bfr[j], acc[i][j], 0, 0, 0);
    __syncthreads();
  }

  const int mBase = m0 + wm * 64, nBase = n0 + wn * 64;
  float bv[4];
#pragma unroll
  for (int j = 0; j < 4; ++j) bv[j] = bias[nBase + j * 16 + l16];
#pragma unroll
  for (int i = 0; i < 4; ++i)
#pragma unroll
    for (int r = 0; r < 4; ++r) {
      const int lrow = mBase + i * 16 + quad * 4 + r;
      const int m = chunkStart + lrow;
      const int b = m >> 12;             // CAP == 4096
      const int tok = selIdx[m];
      float* op = out + ((size_t)b * Tq + tok) * Dq;
#pragma unroll
      for (int j = 0; j < 4; ++j) {
        const int col = nBase + j * 16 + l16;
        op[col] = acc[i][j][r] + bv[j];
      }
    }
}

// ---------- host ----------
extern "C" void kernel_launch(void* const* d_in, const int* in_sizes, int n_in,
                              void* d_out, int out_size, void* d_ws, size_t ws_size,
                              hipStream_t stream) {
  const float* x        = (const float*)d_in[0];
  const float* w_router = (const float*)d_in[1];
  const float* w1       = (const float*)d_in[2];
  const float* b1       = (const float*)d_in[3];
  const float* w2       = (const float*)d_in[4];
  const float* b2       = (const float*)d_in[5];
  float* out = (float*)d_out;

  char* p = (char*)d_ws;
  auto alloc = [&](size_t bytes) {
    char* r = p;
    p += (bytes + 255) & ~(size_t)255;
    return r;
  };
  double* scores          = (double*)alloc((size_t)Bq * Tq * 8);
  int* selIdx             = (int*)alloc((size_t)Mq * 4);
  unsigned char* selFlag  = (unsigned char*)alloc((size_t)Bq * Tq);
  unsigned short* W1t     = (unsigned short*)alloc((size_t)Dq * Fq * 2);  // [F, D]
  unsigned short* W2t     = (unsigned short*)alloc((size_t)Dq * Fq * 2);  // [D, F]
  unsigned short* Xs      = (unsigned short*)alloc((size_t)Mq * Dq * 2);  // [M, D]
  size_t used = (size_t)(p - (char*)d_ws);
  size_t rem = ws_size > used ? ws_size - used : 0;
  int chunkRows = (int)(rem / ((size_t)Fq * 2));
  chunkRows = (chunkRows / 128) * 128;
  if (chunkRows > Mq) chunkRows = Mq;
  if (chunkRows < 128) chunkRows = 128;   // requires ws_size >= ~49.4 MB
  unsigned short* H = (unsigned short*)p;  // [chunkRows, F] bf16

  transpose_f32_to_bf16<<<dim3(Fq / 32, Dq / 32), dim3(32, 8), 0, stream>>>(w1, W1t, Dq, Fq);
  transpose_f32_to_bf16<<<dim3(Dq / 32, Fq / 32), dim3(32, 8), 0, stream>>>(w2, W2t, Fq, Dq);
  scores_kernel<<<2048, 256, 0, stream>>>(x, w_router, scores);
  select_topk<<<Bq, 1024, 0, stream>>>(scores, selIdx, selFlag);
  gather_kernel<<<Mq / 4, 256, 0, stream>>>(x, selIdx, Xs);
  copy_pass<<<(Bq * Tq) / 4, 256, 0, stream>>>(x, selFlag, out);

  for (int r0 = 0; r0 < Mq; r0 += chunkRows) {
    int rows = (Mq - r0 < chunkRows) ? (Mq - r0) : chunkRows;
    int p1 = rows / 128;
    gemm1_gelu<<<32 * p1, 256, 0, stream>>>(Xs + (size_t)r0 * Dq, W1t, b1, H, p1);
    gemm2_scatter<<<8 * p1, 256, 0, stream>>>(H, W2t, b2, selIdx, out, r0, p1);
  }
}